// Round 1
// baseline (4351.458 us; speedup 1.0000x reference)
//
#include <hip/hip_runtime.h>
#include <math.h>

#define L_LEN 110592   // 48*48*48
#define TILE 32
#define NT 3456        // tiles per batch = L_LEN / TILE
#define DIMC 64
#define DI 128         // d_inner

// ---------------------------------------------------------------------------
// Kernel A: in-proj (ssm half) -> depthwise conv(4) + silu -> W_x/W_dt
// projections + softplus gate -> s[b,l,c]; also per-tile channel sums.
// ---------------------------------------------------------------------------
__global__ __launch_bounds__(256) void kA(
    const float* __restrict__ x, const float* __restrict__ W_in,
    const float* __restrict__ conv_w, const float* __restrict__ conv_b,
    const float* __restrict__ W_x, const float* __restrict__ W_dt,
    const float* __restrict__ b_dt,
    float* __restrict__ s, float* __restrict__ sums)
{
    __shared__ float xlds[35 * 64];      // x rows l0-1 .. l0+33
    __shared__ float wlds[64 * 128];     // W_in ssm half [k][c]
    __shared__ float xslds[35 * 128];    // x_ssm_raw rows, later reused for xc
    __shared__ float cwlds[4 * 128];
    __shared__ float psums[256];

    const int t = threadIdx.x;
    const int tile = blockIdx.x;
    const int b = blockIdx.y;
    const int l0 = tile * TILE;
    const long base = (long)b * L_LEN;

    // stage x halo tile
    for (int idx = t; idx < 35 * 64; idx += 256) {
        int r = idx >> 6, col = idx & 63;
        int l = l0 - 1 + r;
        xlds[idx] = (l >= 0 && l < L_LEN) ? x[(base + l) * 64 + col] : 0.f;
    }
    // stage W_in ssm half (cols 0..127)
    for (int idx = t; idx < 64 * 128; idx += 256) {
        int k = idx >> 7, c = idx & 127;
        wlds[idx] = W_in[k * 256 + c];
    }
    for (int idx = t; idx < 4 * 128; idx += 256) cwlds[idx] = conv_w[idx];
    __syncthreads();

    const int c = t & 127;
    const int rg = t >> 7;

    // in-proj: xs[r][c] = x_row[r] . W_in[:,c]
    for (int r = rg; r < 35; r += 2) {
        float acc = 0.f;
        const float4* xr = (const float4*)&xlds[r * 64];
        #pragma unroll
        for (int k4 = 0; k4 < 16; ++k4) {
            float4 xv = xr[k4];
            int k = k4 * 4;
            acc += xv.x * wlds[k * 128 + c] + xv.y * wlds[(k + 1) * 128 + c]
                 + xv.z * wlds[(k + 2) * 128 + c] + xv.w * wlds[(k + 3) * 128 + c];
        }
        xslds[r * 128 + c] = acc;
    }
    __syncthreads();

    // depthwise conv(4) + silu -> registers (16 rows per thread)
    float xcv[16];
    const float cb  = conv_b[c];
    const float cw0 = cwlds[0 * 128 + c], cw1 = cwlds[1 * 128 + c];
    const float cw2 = cwlds[2 * 128 + c], cw3 = cwlds[3 * 128 + c];
    #pragma unroll
    for (int i = 0; i < 16; ++i) {
        int q = rg + 2 * i;                 // local l index 0..31
        float v = xslds[q * 128 + c] * cw0 + xslds[(q + 1) * 128 + c] * cw1
                + xslds[(q + 2) * 128 + c] * cw2 + xslds[(q + 3) * 128 + c] * cw3 + cb;
        xcv[i] = v / (1.f + __expf(-v));    // silu
    }
    __syncthreads();
    // write conv result over xslds rows 0..31 (now indexed [q][c])
    #pragma unroll
    for (int i = 0; i < 16; ++i) xslds[(rg + 2 * i) * 128 + c] = xcv[i];
    __syncthreads();

    // projections: a1 = xc . W_x[:,c]  (c<128 of 144), a2 = xc . W_dt[:,c]
    float a1[16], a2[16];
    #pragma unroll
    for (int i = 0; i < 16; ++i) { a1[i] = 0.f; a2[i] = 0.f; }
    const float bd = b_dt[c];
    for (int k4 = 0; k4 < 128; k4 += 4) {
        float wx0 = W_x[(k4 + 0) * 144 + c], wx1 = W_x[(k4 + 1) * 144 + c];
        float wx2 = W_x[(k4 + 2) * 144 + c], wx3 = W_x[(k4 + 3) * 144 + c];
        float wd0 = W_dt[(k4 + 0) * 128 + c], wd1 = W_dt[(k4 + 1) * 128 + c];
        float wd2 = W_dt[(k4 + 2) * 128 + c], wd3 = W_dt[(k4 + 3) * 128 + c];
        #pragma unroll
        for (int i = 0; i < 16; ++i) {
            const float4 xv = *(const float4*)&xslds[(rg + 2 * i) * 128 + k4];
            a1[i] += xv.x * wx0 + xv.y * wx1 + xv.z * wx2 + xv.w * wx3;
            a2[i] += xv.x * wd0 + xv.y * wd1 + xv.z * wd2 + xv.w * wd3;
        }
    }

    float psum = 0.f;
    #pragma unroll
    for (int i = 0; i < 16; ++i) {
        int q = rg + 2 * i;
        float dv = a2[i] + bd;
        float sp = fmaxf(dv, 0.f) + log1pf(expf(-fabsf(dv)));  // softplus
        float sv = a1[i] * sp;
        s[(base + l0 + q) * 128 + c] = sv;
        psum += sv;
    }
    psums[t] = psum;
    __syncthreads();
    if (t < 128)
        sums[((long)b * NT + tile) * 128 + t] = psums[t] + psums[t + 128];
}

// ---------------------------------------------------------------------------
// Kernel B: exclusive scan of tile sums along tile dim, per (b, c).
// ---------------------------------------------------------------------------
__global__ __launch_bounds__(256) void kB(float* __restrict__ sums)
{
    const int t = threadIdx.x;
    const int b = t >> 7;
    const int c = t & 127;
    const long base = (long)b * NT * 128 + c;
    float run = 0.f;
    for (int tile = 0; tile < NT; tile += 8) {
        float v[8];
        #pragma unroll
        for (int j = 0; j < 8; ++j) v[j] = sums[base + (long)(tile + j) * 128];
        #pragma unroll
        for (int j = 0; j < 8; ++j) {
            sums[base + (long)(tile + j) * 128] = run;
            run += v[j];
        }
    }
}

// ---------------------------------------------------------------------------
// Kernel C: recompute res, in-tile scan -> state, gate, out-proj,
// residual + LayerNorm(64).
// ---------------------------------------------------------------------------
__global__ __launch_bounds__(256) void kC(
    const float* __restrict__ x, const float* __restrict__ W_in,
    const float* __restrict__ W_out, const float* __restrict__ gamma,
    const float* __restrict__ beta,
    const float* __restrict__ s, const float* __restrict__ offs,
    float* __restrict__ out)
{
    __shared__ float xlds[32 * 64];
    __shared__ float wstage[128 * 64];   // W_res [64][128] then W_out [128][64]
    __shared__ float state[32 * 128];

    const int t = threadIdx.x;
    const int tile = blockIdx.x;
    const int b = blockIdx.y;
    const int l0 = tile * TILE;
    const long base = (long)b * L_LEN;

    for (int idx = t; idx < 32 * 64; idx += 256)
        xlds[idx] = x[(base + l0) * 64 + idx];
    // stage W_in res half (cols 128..255) as [k][c]
    for (int idx = t; idx < 64 * 128; idx += 256) {
        int k = idx >> 7, c = idx & 127;
        wstage[idx] = W_in[k * 256 + 128 + c];
    }
    __syncthreads();

    const int c = t & 127;
    const int rg = t >> 7;

    // res = silu(x . W_in[:,128+c])  kept in registers
    float resv[16];
    #pragma unroll
    for (int i = 0; i < 16; ++i) {
        int q = rg + 2 * i;
        float acc = 0.f;
        const float4* xr = (const float4*)&xlds[q * 64];
        #pragma unroll
        for (int k4 = 0; k4 < 16; ++k4) {
            float4 xv = xr[k4];
            int k = k4 * 4;
            acc += xv.x * wstage[k * 128 + c] + xv.y * wstage[(k + 1) * 128 + c]
                 + xv.z * wstage[(k + 2) * 128 + c] + xv.w * wstage[(k + 3) * 128 + c];
        }
        resv[i] = acc / (1.f + __expf(-acc));
    }
    __syncthreads();

    // threads 0..127: sequential in-tile scan; threads 128..255: load W_out
    if (t < 128) {
        float run = offs[((long)b * NT + tile) * 128 + t];
        #pragma unroll 8
        for (int q = 0; q < 32; ++q) {
            run += s[(base + l0 + q) * 128 + t];
            state[q * 128 + t] = run;
        }
    } else {
        for (int idx = t - 128; idx < 128 * 64; idx += 128)
            wstage[idx] = W_out[idx];
    }
    __syncthreads();

    // gate in place: y = state * silu(res)
    #pragma unroll
    for (int i = 0; i < 16; ++i) {
        int q = rg + 2 * i;
        state[q * 128 + c] = state[q * 128 + c] * resv[i];
    }
    __syncthreads();

    // out-proj (128 -> 64) + residual + LayerNorm over 64
    const int d = t & 63;
    const int dg = t >> 6;
    const float g  = gamma[d];
    const float bt = beta[d];
    #pragma unroll
    for (int i = 0; i < 8; ++i) {
        int q = dg + 4 * i;
        float acc = 0.f;
        const float4* yr = (const float4*)&state[q * 128];
        #pragma unroll
        for (int c4 = 0; c4 < 32; ++c4) {
            float4 yv = yr[c4];
            int cc = c4 * 4;
            acc += yv.x * wstage[cc * 64 + d] + yv.y * wstage[(cc + 1) * 64 + d]
                 + yv.z * wstage[(cc + 2) * 64 + d] + yv.w * wstage[(cc + 3) * 64 + d];
        }
        float z = acc + xlds[q * 64 + d];
        float zsum = z;
        #pragma unroll
        for (int off = 32; off > 0; off >>= 1) zsum += __shfl_xor(zsum, off);
        float mu = zsum * 0.015625f;
        float dz = z - mu;
        float vsum = dz * dz;
        #pragma unroll
        for (int off = 32; off > 0; off >>= 1) vsum += __shfl_xor(vsum, off);
        float inv = rsqrtf(vsum * 0.015625f + 1e-3f);
        out[(base + l0 + q) * 64 + d] = g * dz * inv + bt;
    }
}

extern "C" void kernel_launch(void* const* d_in, const int* in_sizes, int n_in,
                              void* d_out, int out_size, void* d_ws, size_t ws_size,
                              hipStream_t stream) {
    const float* x      = (const float*)d_in[0];
    const float* W_in   = (const float*)d_in[1];
    const float* conv_w = (const float*)d_in[2];
    const float* conv_b = (const float*)d_in[3];
    const float* W_x    = (const float*)d_in[4];
    const float* W_dt   = (const float*)d_in[5];
    const float* b_dt   = (const float*)d_in[6];
    const float* W_out  = (const float*)d_in[7];
    const float* gamma  = (const float*)d_in[8];
    const float* beta   = (const float*)d_in[9];
    float* out = (float*)d_out;

    float* s    = (float*)d_ws;                                   // 2*L*128 fp32
    float* sums = (float*)((char*)d_ws + (size_t)2 * L_LEN * 128 * 4);

    dim3 grid(NT, 2);
    kA<<<grid, 256, 0, stream>>>(x, W_in, conv_w, conv_b, W_x, W_dt, b_dt, s, sums);
    kB<<<1, 256, 0, stream>>>(sums);
    kC<<<grid, 256, 0, stream>>>(x, W_in, W_out, gamma, beta, s, sums, out);
}

// Round 2
// 1008.638 us; speedup vs baseline: 4.3142x; 4.3142x over previous
//
#include <hip/hip_runtime.h>
#include <math.h>

#define L_LEN 110592   // 48*48*48
#define TILE 32
#define NT 3456        // tiles per batch = L_LEN / TILE
#define DIMC 64
#define DI 128         // d_inner

// ---------------------------------------------------------------------------
// Kernel A: in-proj (ssm half) -> depthwise conv(4) + silu -> W_x/W_dt
// projections + softplus gate -> s[b,l,c]; also per-tile channel sums.
// ---------------------------------------------------------------------------
__global__ __launch_bounds__(256) void kA(
    const float* __restrict__ x, const float* __restrict__ W_in,
    const float* __restrict__ conv_w, const float* __restrict__ conv_b,
    const float* __restrict__ W_x, const float* __restrict__ W_dt,
    const float* __restrict__ b_dt,
    float* __restrict__ s, float* __restrict__ sums)
{
    __shared__ float xlds[35 * 64];      // x rows l0-1 .. l0+33
    __shared__ float wlds[64 * 128];     // W_in ssm half [k][c]
    __shared__ float xslds[35 * 128];    // x_ssm_raw rows, later reused for xc
    __shared__ float cwlds[4 * 128];
    __shared__ float psums[256];

    const int t = threadIdx.x;
    const int tile = blockIdx.x;
    const int b = blockIdx.y;
    const int l0 = tile * TILE;
    const long base = (long)b * L_LEN;

    // stage x halo tile
    for (int idx = t; idx < 35 * 64; idx += 256) {
        int r = idx >> 6, col = idx & 63;
        int l = l0 - 1 + r;
        xlds[idx] = (l >= 0 && l < L_LEN) ? x[(base + l) * 64 + col] : 0.f;
    }
    // stage W_in ssm half (cols 0..127)
    for (int idx = t; idx < 64 * 128; idx += 256) {
        int k = idx >> 7, c = idx & 127;
        wlds[idx] = W_in[k * 256 + c];
    }
    for (int idx = t; idx < 4 * 128; idx += 256) cwlds[idx] = conv_w[idx];
    __syncthreads();

    const int c = t & 127;
    const int rg = t >> 7;

    // in-proj: xs[r][c] = x_row[r] . W_in[:,c]
    for (int r = rg; r < 35; r += 2) {
        float acc = 0.f;
        const float4* xr = (const float4*)&xlds[r * 64];
        #pragma unroll
        for (int k4 = 0; k4 < 16; ++k4) {
            float4 xv = xr[k4];
            int k = k4 * 4;
            acc += xv.x * wlds[k * 128 + c] + xv.y * wlds[(k + 1) * 128 + c]
                 + xv.z * wlds[(k + 2) * 128 + c] + xv.w * wlds[(k + 3) * 128 + c];
        }
        xslds[r * 128 + c] = acc;
    }
    __syncthreads();

    // depthwise conv(4) + silu -> registers (16 rows per thread)
    float xcv[16];
    const float cb  = conv_b[c];
    const float cw0 = cwlds[0 * 128 + c], cw1 = cwlds[1 * 128 + c];
    const float cw2 = cwlds[2 * 128 + c], cw3 = cwlds[3 * 128 + c];
    #pragma unroll
    for (int i = 0; i < 16; ++i) {
        int q = rg + 2 * i;                 // local l index 0..31
        float v = xslds[q * 128 + c] * cw0 + xslds[(q + 1) * 128 + c] * cw1
                + xslds[(q + 2) * 128 + c] * cw2 + xslds[(q + 3) * 128 + c] * cw3 + cb;
        xcv[i] = v / (1.f + __expf(-v));    // silu
    }
    __syncthreads();
    // write conv result over xslds rows 0..31 (now indexed [q][c])
    #pragma unroll
    for (int i = 0; i < 16; ++i) xslds[(rg + 2 * i) * 128 + c] = xcv[i];
    __syncthreads();

    // projections: a1 = xc . W_x[:,c]  (c<128 of 144), a2 = xc . W_dt[:,c]
    float a1[16], a2[16];
    #pragma unroll
    for (int i = 0; i < 16; ++i) { a1[i] = 0.f; a2[i] = 0.f; }
    const float bd = b_dt[c];
    for (int k4 = 0; k4 < 128; k4 += 4) {
        float wx0 = W_x[(k4 + 0) * 144 + c], wx1 = W_x[(k4 + 1) * 144 + c];
        float wx2 = W_x[(k4 + 2) * 144 + c], wx3 = W_x[(k4 + 3) * 144 + c];
        float wd0 = W_dt[(k4 + 0) * 128 + c], wd1 = W_dt[(k4 + 1) * 128 + c];
        float wd2 = W_dt[(k4 + 2) * 128 + c], wd3 = W_dt[(k4 + 3) * 128 + c];
        #pragma unroll
        for (int i = 0; i < 16; ++i) {
            const float4 xv = *(const float4*)&xslds[(rg + 2 * i) * 128 + k4];
            a1[i] += xv.x * wx0 + xv.y * wx1 + xv.z * wx2 + xv.w * wx3;
            a2[i] += xv.x * wd0 + xv.y * wd1 + xv.z * wd2 + xv.w * wd3;
        }
    }

    float psum = 0.f;
    #pragma unroll
    for (int i = 0; i < 16; ++i) {
        int q = rg + 2 * i;
        float dv = a2[i] + bd;
        float sp = fmaxf(dv, 0.f) + log1pf(expf(-fabsf(dv)));  // softplus
        float sv = a1[i] * sp;
        s[(base + l0 + q) * 128 + c] = sv;
        psum += sv;
    }
    psums[t] = psum;
    __syncthreads();
    if (t < 128)
        sums[((long)b * NT + tile) * 128 + t] = psums[t] + psums[t + 128];
}

// ---------------------------------------------------------------------------
// Kernel B: exclusive scan of tile sums along tile dim, per (b, c).
// Parallel: 8 blocks = 2 batches x 4 c-groups; each thread owns a 432-tile
// chunk of one channel; cross-chunk prefix via LDS.
// ---------------------------------------------------------------------------
#define CHUNK 432   // NT / 8
__global__ __launch_bounds__(256) void kB(float* __restrict__ sums)
{
    __shared__ float tls[256];            // [ct][cc]
    const int cc = threadIdx.x & 31;
    const int ct = threadIdx.x >> 5;      // chunk index 0..7
    const int cg = blockIdx.x;            // c-group 0..3
    const int b  = blockIdx.y;
    const int c  = cg * 32 + cc;
    const long tbase = ((long)b * NT + (long)ct * CHUNK) * 128 + c;

    // pass 1: chunk sum (batched loads for MLP)
    float tot = 0.f;
    for (int j = 0; j < CHUNK; j += 8) {
        float v[8];
        #pragma unroll
        for (int k = 0; k < 8; ++k) v[k] = sums[tbase + (long)(j + k) * 128];
        #pragma unroll
        for (int k = 0; k < 8; ++k) tot += v[k];
    }
    tls[ct * 32 + cc] = tot;
    __syncthreads();

    float run = 0.f;
    #pragma unroll
    for (int p = 0; p < 8; ++p)
        if (p < ct) run += tls[p * 32 + cc];

    // pass 2: rewrite with exclusive prefix
    for (int j = 0; j < CHUNK; j += 8) {
        float v[8];
        #pragma unroll
        for (int k = 0; k < 8; ++k) v[k] = sums[tbase + (long)(j + k) * 128];
        #pragma unroll
        for (int k = 0; k < 8; ++k) {
            sums[tbase + (long)(j + k) * 128] = run;
            run += v[k];
        }
    }
}

// ---------------------------------------------------------------------------
// Kernel C: recompute res (silu into LDS), in-tile scan + gate IN PLACE,
// out-proj, residual + LayerNorm(64). No per-thread arrays live across
// barriers -> no spills.
// ---------------------------------------------------------------------------
__global__ __launch_bounds__(256) void kC(
    const float* __restrict__ x, const float* __restrict__ W_in,
    const float* __restrict__ W_out, const float* __restrict__ gamma,
    const float* __restrict__ beta,
    const float* __restrict__ s, const float* __restrict__ offs,
    float* __restrict__ out)
{
    __shared__ float xlds[32 * 64];      // 8 KB
    __shared__ float wbuf[64 * 128];     // 32 KB: W_in res half, then W_out
    __shared__ float ybuf[32 * 128];     // 16 KB: silu(res), then gated y

    const int t = threadIdx.x;
    const int tile = blockIdx.x;
    const int b = blockIdx.y;
    const int l0 = tile * TILE;
    const long base = (long)b * L_LEN;

    for (int idx = t; idx < 32 * 64; idx += 256)
        xlds[idx] = x[(base + l0) * 64 + idx];
    // stage W_in res half (cols 128..255) as [k][c]
    for (int idx = t; idx < 64 * 128; idx += 256) {
        int k = idx >> 7, c = idx & 127;
        wbuf[idx] = W_in[k * 256 + 128 + c];
    }
    __syncthreads();

    const int c = t & 127;
    const int rg = t >> 7;

    // res = silu(x . W_in[:,128+c]) -> straight to LDS (no register array)
    for (int q = rg; q < 32; q += 2) {
        float acc = 0.f;
        const float4* xr = (const float4*)&xlds[q * 64];
        #pragma unroll
        for (int k4 = 0; k4 < 16; ++k4) {
            float4 xv = xr[k4];
            int k = k4 * 4;
            acc += xv.x * wbuf[k * 128 + c] + xv.y * wbuf[(k + 1) * 128 + c]
                 + xv.z * wbuf[(k + 2) * 128 + c] + xv.w * wbuf[(k + 3) * 128 + c];
        }
        ybuf[q * 128 + c] = acc / (1.f + __expf(-acc));
    }
    __syncthreads();

    // threads 0..127: scan + gate in place; threads 128..255: stage W_out
    if (t < 128) {
        float run = offs[((long)b * NT + tile) * 128 + t];
        #pragma unroll 8
        for (int q = 0; q < 32; ++q) {
            run += s[(base + l0 + q) * 128 + t];
            ybuf[q * 128 + t] *= run;     // y = state * silu(res)
        }
    } else {
        for (int idx = t - 128; idx < 128 * 64; idx += 128)
            wbuf[idx] = W_out[idx];
    }
    __syncthreads();

    // out-proj (128 -> 64) + residual + LayerNorm over 64
    const int d = t & 63;
    const int dg = t >> 6;
    const float g  = gamma[d];
    const float bt = beta[d];
    #pragma unroll 2
    for (int i = 0; i < 8; ++i) {
        int q = dg + 4 * i;
        float acc = 0.f;
        const float4* yr = (const float4*)&ybuf[q * 128];
        #pragma unroll
        for (int c4 = 0; c4 < 32; ++c4) {
            float4 yv = yr[c4];
            int cj = c4 * 4;
            acc += yv.x * wbuf[cj * 64 + d] + yv.y * wbuf[(cj + 1) * 64 + d]
                 + yv.z * wbuf[(cj + 2) * 64 + d] + yv.w * wbuf[(cj + 3) * 64 + d];
        }
        float z = acc + xlds[q * 64 + d];
        float zsum = z;
        #pragma unroll
        for (int off = 32; off > 0; off >>= 1) zsum += __shfl_xor(zsum, off);
        float mu = zsum * 0.015625f;
        float dz = z - mu;
        float vsum = dz * dz;
        #pragma unroll
        for (int off = 32; off > 0; off >>= 1) vsum += __shfl_xor(vsum, off);
        float inv = rsqrtf(vsum * 0.015625f + 1e-3f);
        out[(base + l0 + q) * 64 + d] = g * dz * inv + bt;
    }
}

extern "C" void kernel_launch(void* const* d_in, const int* in_sizes, int n_in,
                              void* d_out, int out_size, void* d_ws, size_t ws_size,
                              hipStream_t stream) {
    const float* x      = (const float*)d_in[0];
    const float* W_in   = (const float*)d_in[1];
    const float* conv_w = (const float*)d_in[2];
    const float* conv_b = (const float*)d_in[3];
    const float* W_x    = (const float*)d_in[4];
    const float* W_dt   = (const float*)d_in[5];
    const float* b_dt   = (const float*)d_in[6];
    const float* W_out  = (const float*)d_in[7];
    const float* gamma  = (const float*)d_in[8];
    const float* beta   = (const float*)d_in[9];
    float* out = (float*)d_out;

    float* s    = (float*)d_ws;                                   // 2*L*128 fp32
    float* sums = (float*)((char*)d_ws + (size_t)2 * L_LEN * 128 * 4);

    dim3 grid(NT, 2);
    kA<<<grid, 256, 0, stream>>>(x, W_in, conv_w, conv_b, W_x, W_dt, b_dt, s, sums);
    dim3 gridB(4, 2);
    kB<<<gridB, 256, 0, stream>>>(sums);
    kC<<<grid, 256, 0, stream>>>(x, W_in, W_out, gamma, beta, s, sums, out);
}

// Round 3
// 623.918 us; speedup vs baseline: 6.9744x; 1.6166x over previous
//
#include <hip/hip_runtime.h>
#include <hip/hip_bf16.h>
#include <math.h>

#define L_LEN 110592   // 48*48*48
#define TILE 32
#define NT 3456        // tiles per batch
#define XROWS (L_LEN + 16)   // xb rows per batch: 1 zero guard front, 15 back

typedef float  floatx4 __attribute__((ext_vector_type(4)));
typedef short  short8  __attribute__((ext_vector_type(8)));

// ---------------------------------------------------------------------------
// kW_x: x (fp32) -> xb (bf16) with guard rows. xb[b][row][k], row = l+1.
// ---------------------------------------------------------------------------
__global__ __launch_bounds__(256) void kW_x(const float* __restrict__ x,
                                            __hip_bfloat16* __restrict__ xb)
{
    long idx = (long)blockIdx.x * 256 + threadIdx.x;   // unit = 4 elements
    const long total = (long)2 * XROWS * 16;
    if (idx >= total) return;
    const int k4 = (int)(idx & 15) << 2;
    const long rowg = idx >> 4;                        // 0..2*XROWS-1
    const int b = (int)(rowg / XROWS);
    const long row = rowg - (long)b * XROWS;
    __hip_bfloat16* dst = xb + (rowg << 6) + k4;
    if (row == 0 || row > L_LEN) {
        dst[0] = __float2bfloat16(0.f); dst[1] = __float2bfloat16(0.f);
        dst[2] = __float2bfloat16(0.f); dst[3] = __float2bfloat16(0.f);
    } else {
        const float4 v = *(const float4*)(x + (((long)b * L_LEN + (row - 1)) << 6) + k4);
        dst[0] = __float2bfloat16(v.x); dst[1] = __float2bfloat16(v.y);
        dst[2] = __float2bfloat16(v.z); dst[3] = __float2bfloat16(v.w);
    }
}

// ---------------------------------------------------------------------------
// kW_w: transposed bf16 weight copies.
//   wti[n][k] = W_in[k][n]        (n<128: ssm half), k=0..63
//   wpt[n][k] = n<128 ? W_x[k][n] : W_dt[k][n-128], k=0..127
// ---------------------------------------------------------------------------
__global__ __launch_bounds__(256) void kW_w(
    const float* __restrict__ W_in, const float* __restrict__ W_x,
    const float* __restrict__ W_dt,
    __hip_bfloat16* __restrict__ wti, __hip_bfloat16* __restrict__ wpt)
{
    const int t = threadIdx.x;
    for (int idx = t; idx < 128 * 64; idx += 256) {
        int n = idx >> 6, k = idx & 63;
        wti[idx] = __float2bfloat16(W_in[k * 256 + n]);
    }
    for (int idx = t; idx < 256 * 128; idx += 256) {
        int n = idx >> 7, k = idx & 127;
        float v = (n < 128) ? W_x[k * 144 + n] : W_dt[k * 128 + (n - 128)];
        wpt[idx] = __float2bfloat16(v);
    }
}

// ---------------------------------------------------------------------------
// kA (MFMA): in-proj -> conv+silu -> projections -> s (bf16) + tile sums.
// A/B fragments read directly from global (xb / wti / wpt); only the conv
// round-trip uses LDS.
// ---------------------------------------------------------------------------
__global__ __launch_bounds__(256) void kA(
    const __hip_bfloat16* __restrict__ xb,
    const __hip_bfloat16* __restrict__ wti,
    const __hip_bfloat16* __restrict__ wpt,
    const float* __restrict__ conv_w, const float* __restrict__ conv_b,
    const float* __restrict__ b_dt,
    __hip_bfloat16* __restrict__ s, float* __restrict__ sums)
{
    __shared__ float xs[128 * 52];            // [c][m] fp32, m=0..47 (pad 52)
    __shared__ __hip_bfloat16 xcb[32 * 136];  // [m][k] bf16 conv output (pad 136)

    const int t = threadIdx.x;
    const int lane = t & 63;
    const int w = t >> 6;          // wave 0..3
    const int quad = lane >> 4;
    const int lr = lane & 15;
    const int tile = blockIdx.x;
    const int b = blockIdx.y;
    const int l0 = tile * TILE;

    // ---- phase 1: in-proj. A rows = l0-1+m (guarded), B = wti. N=32/wave.
    {
        floatx4 acc[3][2] = {};
        const long xrow0 = (long)b * XROWS + l0;   // xb row of A row m=0 is l0 (guard +1)
        #pragma unroll
        for (int ks = 0; ks < 2; ++ks) {
            short8 bfr[2];
            #pragma unroll
            for (int j = 0; j < 2; ++j) {
                const int n = w * 32 + j * 16 + lr;
                bfr[j] = *(const short8*)(wti + (n << 6) + ks * 32 + quad * 8);
            }
            #pragma unroll
            for (int mt = 0; mt < 3; ++mt) {
                short8 afr = *(const short8*)(xb + ((xrow0 + mt * 16 + lr) << 6) + ks * 32 + quad * 8);
                acc[mt][0] = __builtin_amdgcn_mfma_f32_16x16x32_bf16(afr, bfr[0], acc[mt][0], 0, 0, 0);
                acc[mt][1] = __builtin_amdgcn_mfma_f32_16x16x32_bf16(afr, bfr[1], acc[mt][1], 0, 0, 0);
            }
        }
        // D: row = mt*16 + quad*4 + r, col = w*32 + j*16 + lr  -> xs[c][m]
        #pragma unroll
        for (int mt = 0; mt < 3; ++mt)
            #pragma unroll
            for (int j = 0; j < 2; ++j) {
                const int col = w * 32 + j * 16 + lr;
                *(floatx4*)&xs[col * 52 + mt * 16 + quad * 4] = acc[mt][j];
            }
    }
    __syncthreads();

    // ---- phase 2: depthwise conv(4) + silu -> xcb[m][c] bf16
    {
        const int c = t & 127;
        const int m0 = (t >> 7) * 16;
        const float cw0 = conv_w[c], cw1 = conv_w[128 + c];
        const float cw2 = conv_w[256 + c], cw3 = conv_w[384 + c];
        const float cb = conv_b[c];
        float wbuf[20];
        #pragma unroll
        for (int j = 0; j < 5; ++j)
            *(float4*)&wbuf[j * 4] = *(const float4*)&xs[c * 52 + m0 + j * 4];
        #pragma unroll
        for (int i = 0; i < 16; ++i) {
            float v = wbuf[i] * cw0 + wbuf[i + 1] * cw1 + wbuf[i + 2] * cw2
                    + wbuf[i + 3] * cw3 + cb;
            v = v / (1.f + __expf(-v));
            xcb[(m0 + i) * 136 + c] = __float2bfloat16(v);
        }
    }
    __syncthreads();

    // ---- phase 3: projections (a1 = xc.Wx, a2 = xc.Wdt), s + sums
    {
        floatx4 accx[2][2] = {}, accd[2][2] = {};
        #pragma unroll
        for (int ks = 0; ks < 4; ++ks) {
            short8 afr[2];
            #pragma unroll
            for (int mt = 0; mt < 2; ++mt)
                afr[mt] = *(const short8*)&xcb[(mt * 16 + lr) * 136 + ks * 32 + quad * 8];
            #pragma unroll
            for (int j = 0; j < 2; ++j) {
                const int n = w * 32 + j * 16 + lr;
                short8 bx = *(const short8*)(wpt + (n << 7) + ks * 32 + quad * 8);
                short8 bd = *(const short8*)(wpt + ((n + 128) << 7) + ks * 32 + quad * 8);
                #pragma unroll
                for (int mt = 0; mt < 2; ++mt) {
                    accx[mt][j] = __builtin_amdgcn_mfma_f32_16x16x32_bf16(afr[mt], bx, accx[mt][j], 0, 0, 0);
                    accd[mt][j] = __builtin_amdgcn_mfma_f32_16x16x32_bf16(afr[mt], bd, accd[mt][j], 0, 0, 0);
                }
            }
        }
        const long base = (long)b * L_LEN + l0;
        float ps0 = 0.f, ps1 = 0.f;
        #pragma unroll
        for (int j = 0; j < 2; ++j) {
            const int col = w * 32 + j * 16 + lr;
            const float bdv = b_dt[col];
            float psl = 0.f;
            #pragma unroll
            for (int mt = 0; mt < 2; ++mt) {
                #pragma unroll
                for (int r = 0; r < 4; ++r) {
                    float dv = accd[mt][j][r] + bdv;
                    float sp = fmaxf(dv, 0.f) + log1pf(__expf(-fabsf(dv)));
                    float sv = accx[mt][j][r] * sp;
                    __hip_bfloat16 h = __float2bfloat16(sv);
                    s[((base + mt * 16 + quad * 4 + r) << 7) + col] = h;
                    psl += __bfloat162float(h);   // sum the quantized value
                }
            }
            if (j == 0) ps0 = psl; else ps1 = psl;
        }
        ps0 += __shfl_xor(ps0, 16); ps0 += __shfl_xor(ps0, 32);
        ps1 += __shfl_xor(ps1, 16); ps1 += __shfl_xor(ps1, 32);
        const long sb = ((long)b * NT + tile) << 7;
        if (quad == 0)      sums[sb + w * 32 + lr] = ps0;
        else if (quad == 1) sums[sb + w * 32 + 16 + lr] = ps1;
    }
}

// ---------------------------------------------------------------------------
// kB: exclusive scan of tile sums (unchanged).
// ---------------------------------------------------------------------------
#define CHUNK 432   // NT / 8
__global__ __launch_bounds__(256) void kB(float* __restrict__ sums)
{
    __shared__ float tls[256];
    const int cc = threadIdx.x & 31;
    const int ct = threadIdx.x >> 5;
    const int cg = blockIdx.x;
    const int b  = blockIdx.y;
    const int c  = cg * 32 + cc;
    const long tbase = ((long)b * NT + (long)ct * CHUNK) * 128 + c;

    float tot = 0.f;
    for (int j = 0; j < CHUNK; j += 8) {
        float v[8];
        #pragma unroll
        for (int k = 0; k < 8; ++k) v[k] = sums[tbase + (long)(j + k) * 128];
        #pragma unroll
        for (int k = 0; k < 8; ++k) tot += v[k];
    }
    tls[ct * 32 + cc] = tot;
    __syncthreads();

    float run = 0.f;
    #pragma unroll
    for (int p = 0; p < 8; ++p)
        if (p < ct) run += tls[p * 32 + cc];

    for (int j = 0; j < CHUNK; j += 8) {
        float v[8];
        #pragma unroll
        for (int k = 0; k < 8; ++k) v[k] = sums[tbase + (long)(j + k) * 128];
        #pragma unroll
        for (int k = 0; k < 8; ++k) {
            sums[tbase + (long)(j + k) * 128] = run;
            run += v[k];
        }
    }
}

// ---------------------------------------------------------------------------
// kC: res-proj, scan+gate, out-proj, residual+LN. (s now bf16.)
// ---------------------------------------------------------------------------
__global__ __launch_bounds__(256) void kC(
    const float* __restrict__ x, const float* __restrict__ W_in,
    const float* __restrict__ W_out, const float* __restrict__ gamma,
    const float* __restrict__ beta,
    const __hip_bfloat16* __restrict__ s, const float* __restrict__ offs,
    float* __restrict__ out)
{
    __shared__ float xlds[32 * 64];
    __shared__ float wbuf[64 * 128];
    __shared__ float ybuf[32 * 128];

    const int t = threadIdx.x;
    const int tile = blockIdx.x;
    const int b = blockIdx.y;
    const int l0 = tile * TILE;
    const long base = (long)b * L_LEN;

    for (int idx = t; idx < 32 * 64; idx += 256)
        xlds[idx] = x[(base + l0) * 64 + idx];
    for (int idx = t; idx < 64 * 128; idx += 256) {
        int k = idx >> 7, c = idx & 127;
        wbuf[idx] = W_in[k * 256 + 128 + c];
    }
    __syncthreads();

    const int c = t & 127;
    const int rg = t >> 7;

    for (int q = rg; q < 32; q += 2) {
        float acc = 0.f;
        const float4* xr = (const float4*)&xlds[q * 64];
        #pragma unroll
        for (int k4 = 0; k4 < 16; ++k4) {
            float4 xv = xr[k4];
            int k = k4 * 4;
            acc += xv.x * wbuf[k * 128 + c] + xv.y * wbuf[(k + 1) * 128 + c]
                 + xv.z * wbuf[(k + 2) * 128 + c] + xv.w * wbuf[(k + 3) * 128 + c];
        }
        ybuf[q * 128 + c] = acc / (1.f + __expf(-acc));
    }
    __syncthreads();

    if (t < 128) {
        float run = offs[((long)b * NT + tile) * 128 + t];
        const __hip_bfloat16* sp = s + ((base + l0) << 7) + t;
        #pragma unroll 8
        for (int q = 0; q < 32; ++q) {
            run += __bfloat162float(sp[q << 7]);
            ybuf[q * 128 + t] *= run;
        }
    } else {
        for (int idx = t - 128; idx < 128 * 64; idx += 128)
            wbuf[idx] = W_out[idx];
    }
    __syncthreads();

    const int d = t & 63;
    const int dg = t >> 6;
    const float g  = gamma[d];
    const float bt = beta[d];
    #pragma unroll 2
    for (int i = 0; i < 8; ++i) {
        int q = dg + 4 * i;
        float acc = 0.f;
        const float4* yr = (const float4*)&ybuf[q * 128];
        #pragma unroll
        for (int c4 = 0; c4 < 32; ++c4) {
            float4 yv = yr[c4];
            int cj = c4 * 4;
            acc += yv.x * wbuf[cj * 64 + d] + yv.y * wbuf[(cj + 1) * 64 + d]
                 + yv.z * wbuf[(cj + 2) * 64 + d] + yv.w * wbuf[(cj + 3) * 64 + d];
        }
        float z = acc + xlds[q * 64 + d];
        float zsum = z;
        #pragma unroll
        for (int off = 32; off > 0; off >>= 1) zsum += __shfl_xor(zsum, off);
        float mu = zsum * 0.015625f;
        float dz = z - mu;
        float vsum = dz * dz;
        #pragma unroll
        for (int off = 32; off > 0; off >>= 1) vsum += __shfl_xor(vsum, off);
        float inv = rsqrtf(vsum * 0.015625f + 1e-3f);
        out[(base + l0 + q) * 64 + d] = g * dz * inv + bt;
    }
}

extern "C" void kernel_launch(void* const* d_in, const int* in_sizes, int n_in,
                              void* d_out, int out_size, void* d_ws, size_t ws_size,
                              hipStream_t stream) {
    const float* x      = (const float*)d_in[0];
    const float* W_in   = (const float*)d_in[1];
    const float* conv_w = (const float*)d_in[2];
    const float* conv_b = (const float*)d_in[3];
    const float* W_x    = (const float*)d_in[4];
    const float* W_dt   = (const float*)d_in[5];
    const float* b_dt   = (const float*)d_in[6];
    const float* W_out  = (const float*)d_in[7];
    const float* gamma  = (const float*)d_in[8];
    const float* beta   = (const float*)d_in[9];
    float* out = (float*)d_out;

    // workspace layout (bytes)
    __hip_bfloat16* s    = (__hip_bfloat16*)d_ws;                        // 56,623,104
    float*          sums = (float*)((char*)d_ws + 56623104);             //  3,538,944
    __hip_bfloat16* xb   = (__hip_bfloat16*)((char*)d_ws + 60162048);    // 28,315,648
    __hip_bfloat16* wti  = (__hip_bfloat16*)((char*)d_ws + 88477696);    //     16,384
    __hip_bfloat16* wpt  = (__hip_bfloat16*)((char*)d_ws + 88494080);    //     65,536

    const long xconv_units = (long)2 * XROWS * 16;
    kW_x<<<(int)((xconv_units + 255) / 256), 256, 0, stream>>>(x, xb);
    kW_w<<<1, 256, 0, stream>>>(W_in, W_x, W_dt, wti, wpt);
    dim3 grid(NT, 2);
    kA<<<grid, 256, 0, stream>>>(xb, wti, wpt, conv_w, conv_b, b_dt, s, sums);
    dim3 gridB(4, 2);
    kB<<<gridB, 256, 0, stream>>>(sums);
    kC<<<grid, 256, 0, stream>>>(x, W_in, W_out, gamma, beta, s, sums, out);
}

// Round 4
// 357.457 us; speedup vs baseline: 12.1734x; 1.7454x over previous
//
#include <hip/hip_runtime.h>
#include <hip/hip_bf16.h>
#include <math.h>

#define L_LEN 110592   // 48*48*48
#define TILE 32
#define NT 3456        // tiles per batch
#define XROWS (L_LEN + 16)   // xb rows per batch: 1 zero guard front, 15 back

typedef float  floatx4 __attribute__((ext_vector_type(4)));
typedef short  short8  __attribute__((ext_vector_type(8)));

// ---------------------------------------------------------------------------
// kW_x: x (fp32) -> xb (bf16) with guard rows. xb[b][row][k], row = l+1.
// ---------------------------------------------------------------------------
__global__ __launch_bounds__(256) void kW_x(const float* __restrict__ x,
                                            __hip_bfloat16* __restrict__ xb)
{
    long idx = (long)blockIdx.x * 256 + threadIdx.x;   // unit = 4 elements
    const long total = (long)2 * XROWS * 16;
    if (idx >= total) return;
    const int k4 = (int)(idx & 15) << 2;
    const long rowg = idx >> 4;                        // 0..2*XROWS-1
    const int b = (int)(rowg / XROWS);
    const long row = rowg - (long)b * XROWS;
    __hip_bfloat16* dst = xb + (rowg << 6) + k4;
    if (row == 0 || row > L_LEN) {
        dst[0] = __float2bfloat16(0.f); dst[1] = __float2bfloat16(0.f);
        dst[2] = __float2bfloat16(0.f); dst[3] = __float2bfloat16(0.f);
    } else {
        const float4 v = *(const float4*)(x + (((long)b * L_LEN + (row - 1)) << 6) + k4);
        dst[0] = __float2bfloat16(v.x); dst[1] = __float2bfloat16(v.y);
        dst[2] = __float2bfloat16(v.z); dst[3] = __float2bfloat16(v.w);
    }
}

// ---------------------------------------------------------------------------
// kW_w: transposed bf16 weight copies.
//   wti[n][k] = W_in[k][n]          (ssm half), n<128, k<64
//   wpt[n][k] = n<128 ? W_x[k][n] : W_dt[k][n-128], k<128
//   wtr[n][k] = W_in[k][128+n]      (res half), n<128, k<64
//   wot[n][k] = W_out[k][n],        n<64, k<128
// ---------------------------------------------------------------------------
__global__ __launch_bounds__(256) void kW_w(
    const float* __restrict__ W_in, const float* __restrict__ W_x,
    const float* __restrict__ W_dt, const float* __restrict__ W_out,
    __hip_bfloat16* __restrict__ wti, __hip_bfloat16* __restrict__ wpt,
    __hip_bfloat16* __restrict__ wtr, __hip_bfloat16* __restrict__ wot)
{
    const int t = threadIdx.x;
    for (int idx = t; idx < 128 * 64; idx += 256) {
        int n = idx >> 6, k = idx & 63;
        wti[idx] = __float2bfloat16(W_in[k * 256 + n]);
        wtr[idx] = __float2bfloat16(W_in[k * 256 + 128 + n]);
    }
    for (int idx = t; idx < 256 * 128; idx += 256) {
        int n = idx >> 7, k = idx & 127;
        float v = (n < 128) ? W_x[k * 144 + n] : W_dt[k * 128 + (n - 128)];
        wpt[idx] = __float2bfloat16(v);
    }
    for (int idx = t; idx < 64 * 128; idx += 256) {
        int n = idx >> 7, k = idx & 127;
        wot[idx] = __float2bfloat16(W_out[k * 64 + n]);
    }
}

// ---------------------------------------------------------------------------
// kA (MFMA): in-proj -> conv+silu -> projections -> s (bf16) + tile sums.
// ---------------------------------------------------------------------------
__global__ __launch_bounds__(256) void kA(
    const __hip_bfloat16* __restrict__ xb,
    const __hip_bfloat16* __restrict__ wti,
    const __hip_bfloat16* __restrict__ wpt,
    const float* __restrict__ conv_w, const float* __restrict__ conv_b,
    const float* __restrict__ b_dt,
    __hip_bfloat16* __restrict__ s, float* __restrict__ sums)
{
    __shared__ float xs[128 * 52];            // [c][m] fp32, m=0..47 (pad 52)
    __shared__ __hip_bfloat16 xcb[32 * 136];  // [m][k] bf16 conv output

    const int t = threadIdx.x;
    const int lane = t & 63;
    const int w = t >> 6;
    const int quad = lane >> 4;
    const int lr = lane & 15;
    const int tile = blockIdx.x;
    const int b = blockIdx.y;
    const int l0 = tile * TILE;

    // ---- phase 1: in-proj. A rows = l0-1+m (guarded), B = wti.
    {
        floatx4 acc[3][2] = {};
        const long xrow0 = (long)b * XROWS + l0;
        #pragma unroll
        for (int ks = 0; ks < 2; ++ks) {
            short8 bfr[2];
            #pragma unroll
            for (int j = 0; j < 2; ++j) {
                const int n = w * 32 + j * 16 + lr;
                bfr[j] = *(const short8*)(wti + (n << 6) + ks * 32 + quad * 8);
            }
            #pragma unroll
            for (int mt = 0; mt < 3; ++mt) {
                short8 afr = *(const short8*)(xb + ((xrow0 + mt * 16 + lr) << 6) + ks * 32 + quad * 8);
                acc[mt][0] = __builtin_amdgcn_mfma_f32_16x16x32_bf16(afr, bfr[0], acc[mt][0], 0, 0, 0);
                acc[mt][1] = __builtin_amdgcn_mfma_f32_16x16x32_bf16(afr, bfr[1], acc[mt][1], 0, 0, 0);
            }
        }
        #pragma unroll
        for (int mt = 0; mt < 3; ++mt)
            #pragma unroll
            for (int j = 0; j < 2; ++j) {
                const int col = w * 32 + j * 16 + lr;
                *(floatx4*)&xs[col * 52 + mt * 16 + quad * 4] = acc[mt][j];
            }
    }
    __syncthreads();

    // ---- phase 2: depthwise conv(4) + silu -> xcb[m][c] bf16
    {
        const int c = t & 127;
        const int m0 = (t >> 7) * 16;
        const float cw0 = conv_w[c], cw1 = conv_w[128 + c];
        const float cw2 = conv_w[256 + c], cw3 = conv_w[384 + c];
        const float cb = conv_b[c];
        float wbuf[20];
        #pragma unroll
        for (int j = 0; j < 5; ++j)
            *(float4*)&wbuf[j * 4] = *(const float4*)&xs[c * 52 + m0 + j * 4];
        #pragma unroll
        for (int i = 0; i < 16; ++i) {
            float v = wbuf[i] * cw0 + wbuf[i + 1] * cw1 + wbuf[i + 2] * cw2
                    + wbuf[i + 3] * cw3 + cb;
            v = v / (1.f + __expf(-v));
            xcb[(m0 + i) * 136 + c] = __float2bfloat16(v);
        }
    }
    __syncthreads();

    // ---- phase 3: projections, s + sums
    {
        floatx4 accx[2][2] = {}, accd[2][2] = {};
        #pragma unroll
        for (int ks = 0; ks < 4; ++ks) {
            short8 afr[2];
            #pragma unroll
            for (int mt = 0; mt < 2; ++mt)
                afr[mt] = *(const short8*)&xcb[(mt * 16 + lr) * 136 + ks * 32 + quad * 8];
            #pragma unroll
            for (int j = 0; j < 2; ++j) {
                const int n = w * 32 + j * 16 + lr;
                short8 bx = *(const short8*)(wpt + (n << 7) + ks * 32 + quad * 8);
                short8 bd = *(const short8*)(wpt + ((n + 128) << 7) + ks * 32 + quad * 8);
                #pragma unroll
                for (int mt = 0; mt < 2; ++mt) {
                    accx[mt][j] = __builtin_amdgcn_mfma_f32_16x16x32_bf16(afr[mt], bx, accx[mt][j], 0, 0, 0);
                    accd[mt][j] = __builtin_amdgcn_mfma_f32_16x16x32_bf16(afr[mt], bd, accd[mt][j], 0, 0, 0);
                }
            }
        }
        const long base = (long)b * L_LEN + l0;
        float ps0 = 0.f, ps1 = 0.f;
        #pragma unroll
        for (int j = 0; j < 2; ++j) {
            const int col = w * 32 + j * 16 + lr;
            const float bdv = b_dt[col];
            float psl = 0.f;
            #pragma unroll
            for (int mt = 0; mt < 2; ++mt) {
                #pragma unroll
                for (int r = 0; r < 4; ++r) {
                    float dv = accd[mt][j][r] + bdv;
                    float sp = fmaxf(dv, 0.f) + log1pf(__expf(-fabsf(dv)));
                    float sv = accx[mt][j][r] * sp;
                    __hip_bfloat16 h = __float2bfloat16(sv);
                    s[((base + mt * 16 + quad * 4 + r) << 7) + col] = h;
                    psl += __bfloat162float(h);
                }
            }
            if (j == 0) ps0 = psl; else ps1 = psl;
        }
        ps0 += __shfl_xor(ps0, 16); ps0 += __shfl_xor(ps0, 32);
        ps1 += __shfl_xor(ps1, 16); ps1 += __shfl_xor(ps1, 32);
        const long sb = ((long)b * NT + tile) << 7;
        if (quad == 0)      sums[sb + w * 32 + lr] = ps0;
        else if (quad == 1) sums[sb + w * 32 + 16 + lr] = ps1;
    }
}

// ---------------------------------------------------------------------------
// kB: exclusive scan of tile sums.
// ---------------------------------------------------------------------------
#define CHUNK 432   // NT / 8
__global__ __launch_bounds__(256) void kB(float* __restrict__ sums)
{
    __shared__ float tls[256];
    const int cc = threadIdx.x & 31;
    const int ct = threadIdx.x >> 5;
    const int cg = blockIdx.x;
    const int b  = blockIdx.y;
    const int c  = cg * 32 + cc;
    const long tbase = ((long)b * NT + (long)ct * CHUNK) * 128 + c;

    float tot = 0.f;
    for (int j = 0; j < CHUNK; j += 8) {
        float v[8];
        #pragma unroll
        for (int k = 0; k < 8; ++k) v[k] = sums[tbase + (long)(j + k) * 128];
        #pragma unroll
        for (int k = 0; k < 8; ++k) tot += v[k];
    }
    tls[ct * 32 + cc] = tot;
    __syncthreads();

    float run = 0.f;
    #pragma unroll
    for (int p = 0; p < 8; ++p)
        if (p < ct) run += tls[p * 32 + cc];

    for (int j = 0; j < CHUNK; j += 8) {
        float v[8];
        #pragma unroll
        for (int k = 0; k < 8; ++k) v[k] = sums[tbase + (long)(j + k) * 128];
        #pragma unroll
        for (int k = 0; k < 8; ++k) {
            sums[tbase + (long)(j + k) * 128] = run;
            run += v[k];
        }
    }
}

// ---------------------------------------------------------------------------
// kC (MFMA): res-proj MFMA -> silu -> scan+gate -> out-proj MFMA ->
// residual + LayerNorm(64).
// ---------------------------------------------------------------------------
__global__ __launch_bounds__(256) void kC(
    const float* __restrict__ x,
    const __hip_bfloat16* __restrict__ xb,
    const __hip_bfloat16* __restrict__ wtr,
    const __hip_bfloat16* __restrict__ wot,
    const float* __restrict__ gamma, const float* __restrict__ beta,
    const __hip_bfloat16* __restrict__ s, const float* __restrict__ offs,
    float* __restrict__ out)
{
    __shared__ float resf[32 * 128];          // 16 KB; reused as zbuf after scan
    __shared__ __hip_bfloat16 ybf[32 * 136];  // 8.5 KB: gated y, bf16 A-layout

    const int t = threadIdx.x;
    const int lane = t & 63;
    const int w = t >> 6;
    const int quad = lane >> 4;
    const int lr = lane & 15;
    const int tile = blockIdx.x;
    const int b = blockIdx.y;
    const int l0 = tile * TILE;
    const long base = (long)b * L_LEN;

    // ---- phase 1: res-proj MFMA (M=32, N=128, K=64), silu -> resf[m][c]
    {
        floatx4 acc[2][2] = {};
        const long xrow0 = (long)b * XROWS + l0 + 1;   // xb row of x[l0]
        #pragma unroll
        for (int ks = 0; ks < 2; ++ks) {
            short8 bfr[2];
            #pragma unroll
            for (int j = 0; j < 2; ++j) {
                const int n = w * 32 + j * 16 + lr;
                bfr[j] = *(const short8*)(wtr + (n << 6) + ks * 32 + quad * 8);
            }
            #pragma unroll
            for (int mt = 0; mt < 2; ++mt) {
                short8 afr = *(const short8*)(xb + ((xrow0 + mt * 16 + lr) << 6) + ks * 32 + quad * 8);
                acc[mt][0] = __builtin_amdgcn_mfma_f32_16x16x32_bf16(afr, bfr[0], acc[mt][0], 0, 0, 0);
                acc[mt][1] = __builtin_amdgcn_mfma_f32_16x16x32_bf16(afr, bfr[1], acc[mt][1], 0, 0, 0);
            }
        }
        #pragma unroll
        for (int mt = 0; mt < 2; ++mt)
            #pragma unroll
            for (int j = 0; j < 2; ++j) {
                const int col = w * 32 + j * 16 + lr;
                #pragma unroll
                for (int r = 0; r < 4; ++r) {
                    float v = acc[mt][j][r];
                    resf[(mt * 16 + quad * 4 + r) * 128 + col] = v / (1.f + __expf(-v));
                }
            }
    }
    __syncthreads();

    // ---- phase 2: scan + gate (threads 0..127), y -> ybf bf16
    if (t < 128) {
        float run = offs[((long)b * NT + tile) * 128 + t];
        const __hip_bfloat16* sp = s + ((base + l0) << 7) + t;
        #pragma unroll 8
        for (int q = 0; q < 32; ++q) {
            run += __bfloat162float(sp[q << 7]);
            ybf[q * 136 + t] = __float2bfloat16(resf[q * 128 + t] * run);
        }
    }
    __syncthreads();

    // ---- phase 3: out-proj MFMA (M=32, N=64, K=128) -> zbuf (=resf) [m][68]
    {
        float* zbuf = resf;                  // resf dead after scan
        floatx4 acc[2] = {};
        const int n = w * 16 + lr;
        #pragma unroll
        for (int ks = 0; ks < 4; ++ks) {
            short8 bfr = *(const short8*)(wot + (n << 7) + ks * 32 + quad * 8);
            #pragma unroll
            for (int mt = 0; mt < 2; ++mt) {
                short8 afr = *(const short8*)&ybf[(mt * 16 + lr) * 136 + ks * 32 + quad * 8];
                acc[mt] = __builtin_amdgcn_mfma_f32_16x16x32_bf16(afr, bfr, acc[mt], 0, 0, 0);
            }
        }
        __syncthreads();                     // ensure all scan reads of resf done
        #pragma unroll
        for (int mt = 0; mt < 2; ++mt)
            #pragma unroll
            for (int r = 0; r < 4; ++r)
                zbuf[(mt * 16 + quad * 4 + r) * 68 + n] = acc[mt][r];
    }
    __syncthreads();

    // ---- phase 4: residual + LayerNorm(64)
    {
        const float* zbuf = resf;
        const int d = t & 63;
        const int dg = t >> 6;
        const float g  = gamma[d];
        const float bt = beta[d];
        #pragma unroll 2
        for (int i = 0; i < 8; ++i) {
            int q = dg + 4 * i;
            float z = zbuf[q * 68 + d] + x[(base + l0 + q) * 64 + d];
            float zsum = z;
            #pragma unroll
            for (int off = 32; off > 0; off >>= 1) zsum += __shfl_xor(zsum, off);
            float mu = zsum * 0.015625f;
            float dz = z - mu;
            float vsum = dz * dz;
            #pragma unroll
            for (int off = 32; off > 0; off >>= 1) vsum += __shfl_xor(vsum, off);
            float inv = rsqrtf(vsum * 0.015625f + 1e-3f);
            out[(base + l0 + q) * 64 + d] = g * dz * inv + bt;
        }
    }
}

extern "C" void kernel_launch(void* const* d_in, const int* in_sizes, int n_in,
                              void* d_out, int out_size, void* d_ws, size_t ws_size,
                              hipStream_t stream) {
    const float* x      = (const float*)d_in[0];
    const float* W_in   = (const float*)d_in[1];
    const float* conv_w = (const float*)d_in[2];
    const float* conv_b = (const float*)d_in[3];
    const float* W_x    = (const float*)d_in[4];
    const float* W_dt   = (const float*)d_in[5];
    const float* b_dt   = (const float*)d_in[6];
    const float* W_out  = (const float*)d_in[7];
    const float* gamma  = (const float*)d_in[8];
    const float* beta   = (const float*)d_in[9];
    float* out = (float*)d_out;

    // workspace layout (bytes)
    __hip_bfloat16* s    = (__hip_bfloat16*)d_ws;                        // 56,623,104
    float*          sums = (float*)((char*)d_ws + 56623104);             //  3,538,944
    __hip_bfloat16* xb   = (__hip_bfloat16*)((char*)d_ws + 60162048);    // 28,315,648
    __hip_bfloat16* wti  = (__hip_bfloat16*)((char*)d_ws + 88477696);    //     16,384
    __hip_bfloat16* wpt  = (__hip_bfloat16*)((char*)d_ws + 88494080);    //     65,536
    __hip_bfloat16* wtr  = (__hip_bfloat16*)((char*)d_ws + 88559616);    //     16,384
    __hip_bfloat16* wot  = (__hip_bfloat16*)((char*)d_ws + 88576000);    //     16,384

    const long xconv_units = (long)2 * XROWS * 16;
    kW_x<<<(int)((xconv_units + 255) / 256), 256, 0, stream>>>(x, xb);
    kW_w<<<1, 256, 0, stream>>>(W_in, W_x, W_dt, W_out, wti, wpt, wtr, wot);
    dim3 grid(NT, 2);
    kA<<<grid, 256, 0, stream>>>(xb, wti, wpt, conv_w, conv_b, b_dt, s, sums);
    dim3 gridB(4, 2);
    kB<<<gridB, 256, 0, stream>>>(sums);
    kC<<<grid, 256, 0, stream>>>(x, xb, wtr, wot, gamma, beta, s, sums, out);
}

// Round 5
// 321.373 us; speedup vs baseline: 13.5402x; 1.1123x over previous
//
#include <hip/hip_runtime.h>
#include <hip/hip_bf16.h>
#include <math.h>

#define L_LEN 110592   // 48*48*48
#define TILE 32
#define NT 3456        // tiles per batch
#define XROWS (L_LEN + 16)   // xb rows per batch: 1 zero guard front, 15 back

typedef float  floatx4 __attribute__((ext_vector_type(4)));
typedef short  short8  __attribute__((ext_vector_type(8)));

// fast silu: v * rcp(1+exp(-v))  (v_exp + v_rcp, ~5 VALU)
__device__ __forceinline__ float fast_silu(float v) {
    return v * __builtin_amdgcn_rcpf(1.f + __expf(-v));
}
// fast softplus: max(d,0) + log(1+exp(-|d|))  (v_exp + v_log, ~8 VALU)
__device__ __forceinline__ float fast_softplus(float d) {
    return fmaxf(d, 0.f) + __logf(1.f + __expf(-fabsf(d)));
}

// ---------------------------------------------------------------------------
// kW_x: x (fp32) -> xb (bf16) with guard rows. xb[b][row][k], row = l+1.
// ---------------------------------------------------------------------------
__global__ __launch_bounds__(256) void kW_x(const float* __restrict__ x,
                                            __hip_bfloat16* __restrict__ xb)
{
    long idx = (long)blockIdx.x * 256 + threadIdx.x;   // unit = 4 elements
    const long total = (long)2 * XROWS * 16;
    if (idx >= total) return;
    const int k4 = (int)(idx & 15) << 2;
    const long rowg = idx >> 4;                        // 0..2*XROWS-1
    const int b = (int)(rowg / XROWS);
    const long row = rowg - (long)b * XROWS;
    __hip_bfloat16* dst = xb + (rowg << 6) + k4;
    if (row == 0 || row > L_LEN) {
        dst[0] = __float2bfloat16(0.f); dst[1] = __float2bfloat16(0.f);
        dst[2] = __float2bfloat16(0.f); dst[3] = __float2bfloat16(0.f);
    } else {
        const float4 v = *(const float4*)(x + (((long)b * L_LEN + (row - 1)) << 6) + k4);
        dst[0] = __float2bfloat16(v.x); dst[1] = __float2bfloat16(v.y);
        dst[2] = __float2bfloat16(v.z); dst[3] = __float2bfloat16(v.w);
    }
}

// ---------------------------------------------------------------------------
// kW_w: transposed bf16 weight copies.
// ---------------------------------------------------------------------------
__global__ __launch_bounds__(256) void kW_w(
    const float* __restrict__ W_in, const float* __restrict__ W_x,
    const float* __restrict__ W_dt, const float* __restrict__ W_out,
    __hip_bfloat16* __restrict__ wti, __hip_bfloat16* __restrict__ wpt,
    __hip_bfloat16* __restrict__ wtr, __hip_bfloat16* __restrict__ wot)
{
    const int t = threadIdx.x;
    for (int idx = t; idx < 128 * 64; idx += 256) {
        int n = idx >> 6, k = idx & 63;
        wti[idx] = __float2bfloat16(W_in[k * 256 + n]);
        wtr[idx] = __float2bfloat16(W_in[k * 256 + 128 + n]);
    }
    for (int idx = t; idx < 256 * 128; idx += 256) {
        int n = idx >> 7, k = idx & 127;
        float v = (n < 128) ? W_x[k * 144 + n] : W_dt[k * 128 + (n - 128)];
        wpt[idx] = __float2bfloat16(v);
    }
    for (int idx = t; idx < 64 * 128; idx += 256) {
        int n = idx >> 7, k = idx & 127;
        wot[idx] = __float2bfloat16(W_out[k * 64 + n]);
    }
}

// ---------------------------------------------------------------------------
// kA (MFMA): in-proj -> conv+silu -> projections -> s (bf16) + tile sums.
// ---------------------------------------------------------------------------
__global__ __launch_bounds__(256) void kA(
    const __hip_bfloat16* __restrict__ xb,
    const __hip_bfloat16* __restrict__ wti,
    const __hip_bfloat16* __restrict__ wpt,
    const float* __restrict__ conv_w, const float* __restrict__ conv_b,
    const float* __restrict__ b_dt,
    __hip_bfloat16* __restrict__ s, float* __restrict__ sums)
{
    __shared__ float xs[128 * 52];            // [c][m] fp32, m=0..47 (pad 52)
    __shared__ __hip_bfloat16 xcb[32 * 136];  // [m][k] bf16 conv output

    const int t = threadIdx.x;
    const int lane = t & 63;
    const int w = t >> 6;
    const int quad = lane >> 4;
    const int lr = lane & 15;
    const int tile = blockIdx.x;
    const int b = blockIdx.y;
    const int l0 = tile * TILE;

    // ---- phase 1: in-proj. A rows = l0-1+m (guarded), B = wti.
    {
        floatx4 acc[3][2] = {};
        const long xrow0 = (long)b * XROWS + l0;
        #pragma unroll
        for (int ks = 0; ks < 2; ++ks) {
            short8 bfr[2];
            #pragma unroll
            for (int j = 0; j < 2; ++j) {
                const int n = w * 32 + j * 16 + lr;
                bfr[j] = *(const short8*)(wti + (n << 6) + ks * 32 + quad * 8);
            }
            #pragma unroll
            for (int mt = 0; mt < 3; ++mt) {
                short8 afr = *(const short8*)(xb + ((xrow0 + mt * 16 + lr) << 6) + ks * 32 + quad * 8);
                acc[mt][0] = __builtin_amdgcn_mfma_f32_16x16x32_bf16(afr, bfr[0], acc[mt][0], 0, 0, 0);
                acc[mt][1] = __builtin_amdgcn_mfma_f32_16x16x32_bf16(afr, bfr[1], acc[mt][1], 0, 0, 0);
            }
        }
        #pragma unroll
        for (int mt = 0; mt < 3; ++mt)
            #pragma unroll
            for (int j = 0; j < 2; ++j) {
                const int col = w * 32 + j * 16 + lr;
                *(floatx4*)&xs[col * 52 + mt * 16 + quad * 4] = acc[mt][j];
            }
    }
    __syncthreads();

    // ---- phase 2: depthwise conv(4) + silu -> xcb[m][c] bf16
    {
        const int c = t & 127;
        const int m0 = (t >> 7) * 16;
        const float cw0 = conv_w[c], cw1 = conv_w[128 + c];
        const float cw2 = conv_w[256 + c], cw3 = conv_w[384 + c];
        const float cb = conv_b[c];
        float wbuf[20];
        #pragma unroll
        for (int j = 0; j < 5; ++j)
            *(float4*)&wbuf[j * 4] = *(const float4*)&xs[c * 52 + m0 + j * 4];
        #pragma unroll
        for (int i = 0; i < 16; ++i) {
            float v = wbuf[i] * cw0 + wbuf[i + 1] * cw1 + wbuf[i + 2] * cw2
                    + wbuf[i + 3] * cw3 + cb;
            xcb[(m0 + i) * 136 + c] = __float2bfloat16(fast_silu(v));
        }
    }
    __syncthreads();

    // ---- phase 3: projections, s + sums
    {
        floatx4 accx[2][2] = {}, accd[2][2] = {};
        #pragma unroll
        for (int ks = 0; ks < 4; ++ks) {
            short8 afr[2];
            #pragma unroll
            for (int mt = 0; mt < 2; ++mt)
                afr[mt] = *(const short8*)&xcb[(mt * 16 + lr) * 136 + ks * 32 + quad * 8];
            #pragma unroll
            for (int j = 0; j < 2; ++j) {
                const int n = w * 32 + j * 16 + lr;
                short8 bx = *(const short8*)(wpt + (n << 7) + ks * 32 + quad * 8);
                short8 bd = *(const short8*)(wpt + ((n + 128) << 7) + ks * 32 + quad * 8);
                #pragma unroll
                for (int mt = 0; mt < 2; ++mt) {
                    accx[mt][j] = __builtin_amdgcn_mfma_f32_16x16x32_bf16(afr[mt], bx, accx[mt][j], 0, 0, 0);
                    accd[mt][j] = __builtin_amdgcn_mfma_f32_16x16x32_bf16(afr[mt], bd, accd[mt][j], 0, 0, 0);
                }
            }
        }
        const long base = (long)b * L_LEN + l0;
        float ps0 = 0.f, ps1 = 0.f;
        #pragma unroll
        for (int j = 0; j < 2; ++j) {
            const int col = w * 32 + j * 16 + lr;
            const float bdv = b_dt[col];
            float psl = 0.f;
            #pragma unroll
            for (int mt = 0; mt < 2; ++mt) {
                #pragma unroll
                for (int r = 0; r < 4; ++r) {
                    float dv = accd[mt][j][r] + bdv;
                    float sv = accx[mt][j][r] * fast_softplus(dv);
                    __hip_bfloat16 h = __float2bfloat16(sv);
                    s[((base + mt * 16 + quad * 4 + r) << 7) + col] = h;
                    psl += __bfloat162float(h);
                }
            }
            if (j == 0) ps0 = psl; else ps1 = psl;
        }
        ps0 += __shfl_xor(ps0, 16); ps0 += __shfl_xor(ps0, 32);
        ps1 += __shfl_xor(ps1, 16); ps1 += __shfl_xor(ps1, 32);
        const long sb = ((long)b * NT + tile) << 7;
        if (quad == 0)      sums[sb + w * 32 + lr] = ps0;
        else if (quad == 1) sums[sb + w * 32 + 16 + lr] = ps1;
    }
}

// ---------------------------------------------------------------------------
// kB: exclusive scan of tile sums.
// ---------------------------------------------------------------------------
#define CHUNK 432   // NT / 8
__global__ __launch_bounds__(256) void kB(float* __restrict__ sums)
{
    __shared__ float tls[256];
    const int cc = threadIdx.x & 31;
    const int ct = threadIdx.x >> 5;
    const int cg = blockIdx.x;
    const int b  = blockIdx.y;
    const int c  = cg * 32 + cc;
    const long tbase = ((long)b * NT + (long)ct * CHUNK) * 128 + c;

    float tot = 0.f;
    for (int j = 0; j < CHUNK; j += 8) {
        float v[8];
        #pragma unroll
        for (int k = 0; k < 8; ++k) v[k] = sums[tbase + (long)(j + k) * 128];
        #pragma unroll
        for (int k = 0; k < 8; ++k) tot += v[k];
    }
    tls[ct * 32 + cc] = tot;
    __syncthreads();

    float run = 0.f;
    #pragma unroll
    for (int p = 0; p < 8; ++p)
        if (p < ct) run += tls[p * 32 + cc];

    for (int j = 0; j < CHUNK; j += 8) {
        float v[8];
        #pragma unroll
        for (int k = 0; k < 8; ++k) v[k] = sums[tbase + (long)(j + k) * 128];
        #pragma unroll
        for (int k = 0; k < 8; ++k) {
            sums[tbase + (long)(j + k) * 128] = run;
            run += v[k];
        }
    }
}

// ---------------------------------------------------------------------------
// kC (MFMA): res-proj MFMA -> silu -> scan+gate -> out-proj MFMA ->
// residual + LayerNorm(64).
// ---------------------------------------------------------------------------
__global__ __launch_bounds__(256) void kC(
    const float* __restrict__ x,
    const __hip_bfloat16* __restrict__ xb,
    const __hip_bfloat16* __restrict__ wtr,
    const __hip_bfloat16* __restrict__ wot,
    const float* __restrict__ gamma, const float* __restrict__ beta,
    const __hip_bfloat16* __restrict__ s, const float* __restrict__ offs,
    float* __restrict__ out)
{
    __shared__ float resf[32 * 128];          // 16 KB; reused as zbuf after scan
    __shared__ __hip_bfloat16 ybf[32 * 136];  // 8.5 KB: gated y, bf16 A-layout

    const int t = threadIdx.x;
    const int lane = t & 63;
    const int w = t >> 6;
    const int quad = lane >> 4;
    const int lr = lane & 15;
    const int tile = blockIdx.x;
    const int b = blockIdx.y;
    const int l0 = tile * TILE;
    const long base = (long)b * L_LEN;

    // ---- phase 1: res-proj MFMA (M=32, N=128, K=64), silu -> resf[m][c]
    {
        floatx4 acc[2][2] = {};
        const long xrow0 = (long)b * XROWS + l0 + 1;   // xb row of x[l0]
        #pragma unroll
        for (int ks = 0; ks < 2; ++ks) {
            short8 bfr[2];
            #pragma unroll
            for (int j = 0; j < 2; ++j) {
                const int n = w * 32 + j * 16 + lr;
                bfr[j] = *(const short8*)(wtr + (n << 6) + ks * 32 + quad * 8);
            }
            #pragma unroll
            for (int mt = 0; mt < 2; ++mt) {
                short8 afr = *(const short8*)(xb + ((xrow0 + mt * 16 + lr) << 6) + ks * 32 + quad * 8);
                acc[mt][0] = __builtin_amdgcn_mfma_f32_16x16x32_bf16(afr, bfr[0], acc[mt][0], 0, 0, 0);
                acc[mt][1] = __builtin_amdgcn_mfma_f32_16x16x32_bf16(afr, bfr[1], acc[mt][1], 0, 0, 0);
            }
        }
        #pragma unroll
        for (int mt = 0; mt < 2; ++mt)
            #pragma unroll
            for (int j = 0; j < 2; ++j) {
                const int col = w * 32 + j * 16 + lr;
                #pragma unroll
                for (int r = 0; r < 4; ++r) {
                    float v = acc[mt][j][r];
                    resf[(mt * 16 + quad * 4 + r) * 128 + col] = fast_silu(v);
                }
            }
    }
    __syncthreads();

    // ---- phase 2: scan + gate (threads 0..127), y -> ybf bf16
    if (t < 128) {
        float run = offs[((long)b * NT + tile) * 128 + t];
        const __hip_bfloat16* sp = s + ((base + l0) << 7) + t;
        #pragma unroll 8
        for (int q = 0; q < 32; ++q) {
            run += __bfloat162float(sp[q << 7]);
            ybf[q * 136 + t] = __float2bfloat16(resf[q * 128 + t] * run);
        }
    }
    __syncthreads();

    // ---- phase 3: out-proj MFMA (M=32, N=64, K=128) -> zbuf (=resf) [m][68]
    {
        float* zbuf = resf;                  // resf dead after scan
        floatx4 acc[2] = {};
        const int n = w * 16 + lr;
        #pragma unroll
        for (int ks = 0; ks < 4; ++ks) {
            short8 bfr = *(const short8*)(wot + (n << 7) + ks * 32 + quad * 8);
            #pragma unroll
            for (int mt = 0; mt < 2; ++mt) {
                short8 afr = *(const short8*)&ybf[(mt * 16 + lr) * 136 + ks * 32 + quad * 8];
                acc[mt] = __builtin_amdgcn_mfma_f32_16x16x32_bf16(afr, bfr, acc[mt], 0, 0, 0);
            }
        }
        __syncthreads();                     // ensure all scan reads of resf done
        #pragma unroll
        for (int mt = 0; mt < 2; ++mt)
            #pragma unroll
            for (int r = 0; r < 4; ++r)
                zbuf[(mt * 16 + quad * 4 + r) * 68 + n] = acc[mt][r];
    }
    __syncthreads();

    // ---- phase 4: residual + LayerNorm(64)
    {
        const float* zbuf = resf;
        const int d = t & 63;
        const int dg = t >> 6;
        const float g  = gamma[d];
        const float bt = beta[d];
        #pragma unroll 2
        for (int i = 0; i < 8; ++i) {
            int q = dg + 4 * i;
            float z = zbuf[q * 68 + d] + x[(base + l0 + q) * 64 + d];
            float zsum = z;
            #pragma unroll
            for (int off = 32; off > 0; off >>= 1) zsum += __shfl_xor(zsum, off);
            float mu = zsum * 0.015625f;
            float dz = z - mu;
            float vsum = dz * dz;
            #pragma unroll
            for (int off = 32; off > 0; off >>= 1) vsum += __shfl_xor(vsum, off);
            float inv = rsqrtf(vsum * 0.015625f + 1e-3f);
            out[(base + l0 + q) * 64 + d] = g * dz * inv + bt;
        }
    }
}

extern "C" void kernel_launch(void* const* d_in, const int* in_sizes, int n_in,
                              void* d_out, int out_size, void* d_ws, size_t ws_size,
                              hipStream_t stream) {
    const float* x      = (const float*)d_in[0];
    const float* W_in   = (const float*)d_in[1];
    const float* conv_w = (const float*)d_in[2];
    const float* conv_b = (const float*)d_in[3];
    const float* W_x    = (const float*)d_in[4];
    const float* W_dt   = (const float*)d_in[5];
    const float* b_dt   = (const float*)d_in[6];
    const float* W_out  = (const float*)d_in[7];
    const float* gamma  = (const float*)d_in[8];
    const float* beta   = (const float*)d_in[9];
    float* out = (float*)d_out;

    // workspace layout (bytes)
    __hip_bfloat16* s    = (__hip_bfloat16*)d_ws;                        // 56,623,104
    float*          sums = (float*)((char*)d_ws + 56623104);             //  3,538,944
    __hip_bfloat16* xb   = (__hip_bfloat16*)((char*)d_ws + 60162048);    // 28,315,648
    __hip_bfloat16* wti  = (__hip_bfloat16*)((char*)d_ws + 88477696);    //     16,384
    __hip_bfloat16* wpt  = (__hip_bfloat16*)((char*)d_ws + 88494080);    //     65,536
    __hip_bfloat16* wtr  = (__hip_bfloat16*)((char*)d_ws + 88559616);    //     16,384
    __hip_bfloat16* wot  = (__hip_bfloat16*)((char*)d_ws + 88576000);    //     16,384

    const long xconv_units = (long)2 * XROWS * 16;
    kW_x<<<(int)((xconv_units + 255) / 256), 256, 0, stream>>>(x, xb);
    kW_w<<<1, 256, 0, stream>>>(W_in, W_x, W_dt, W_out, wti, wpt, wtr, wot);
    dim3 grid(NT, 2);
    kA<<<grid, 256, 0, stream>>>(xb, wti, wpt, conv_w, conv_b, b_dt, s, sums);
    dim3 gridB(4, 2);
    kB<<<gridB, 256, 0, stream>>>(sums);
    kC<<<grid, 256, 0, stream>>>(x, xb, wtr, wot, gamma, beta, s, sums, out);
}

// Round 6
// 317.801 us; speedup vs baseline: 13.6924x; 1.0112x over previous
//
#include <hip/hip_runtime.h>
#include <hip/hip_bf16.h>
#include <math.h>

#define L_LEN 110592   // 48*48*48
#define TILE 32
#define NT 3456        // tiles per batch
#define NCH 64         // scan chunks per batch
#define TPC 54         // tiles per chunk (NT/NCH)
#define XS_S 60        // xs LDS stride (bf16): 120B row stride -> 4-way banks max

typedef float  floatx4 __attribute__((ext_vector_type(4)));
typedef short  short8  __attribute__((ext_vector_type(8)));
typedef short  short4v __attribute__((ext_vector_type(4)));

// fast silu: v * rcp(1+exp(-v))
__device__ __forceinline__ float fast_silu(float v) {
    return v * __builtin_amdgcn_rcpf(1.f + __expf(-v));
}
// fast softplus: max(d,0) + log(1+exp(-|d|))
__device__ __forceinline__ float fast_softplus(float d) {
    return fmaxf(d, 0.f) + __logf(1.f + __expf(-fabsf(d)));
}
__device__ __forceinline__ short f2bf(float f) {
    __hip_bfloat16 h = __float2bfloat16(f);
    return *reinterpret_cast<short*>(&h);
}
__device__ __forceinline__ float bf2f(short s) {
    __hip_bfloat16 h = *reinterpret_cast<__hip_bfloat16*>(&s);
    return __bfloat162float(h);
}
__device__ __forceinline__ short8 pack_bf8(float4 a, float4 b) {
    short8 r;
    r[0] = f2bf(a.x); r[1] = f2bf(a.y); r[2] = f2bf(a.z); r[3] = f2bf(a.w);
    r[4] = f2bf(b.x); r[5] = f2bf(b.y); r[6] = f2bf(b.z); r[7] = f2bf(b.w);
    return r;
}

// ---------------------------------------------------------------------------
// kW_w: transposed bf16 weight copies.
//   wti[n][k] = W_in[k][n] (ssm), wtr[n][k] = W_in[k][128+n] (res), k<64
//   wpt[n][k] = n<128 ? W_x[k][n] : W_dt[k][n-128], k<128
//   wot[n][k] = W_out[k][n], n<64, k<128
// ---------------------------------------------------------------------------
__global__ __launch_bounds__(256) void kW_w(
    const float* __restrict__ W_in, const float* __restrict__ W_x,
    const float* __restrict__ W_dt, const float* __restrict__ W_out,
    __hip_bfloat16* __restrict__ wti, __hip_bfloat16* __restrict__ wpt,
    __hip_bfloat16* __restrict__ wtr, __hip_bfloat16* __restrict__ wot)
{
    const int t = threadIdx.x;
    for (int idx = t; idx < 128 * 64; idx += 256) {
        int n = idx >> 6, k = idx & 63;
        wti[idx] = __float2bfloat16(W_in[k * 256 + n]);
        wtr[idx] = __float2bfloat16(W_in[k * 256 + 128 + n]);
    }
    for (int idx = t; idx < 256 * 128; idx += 256) {
        int n = idx >> 7, k = idx & 127;
        float v = (n < 128) ? W_x[k * 144 + n] : W_dt[k * 128 + (n - 128)];
        wpt[idx] = __float2bfloat16(v);
    }
    for (int idx = t; idx < 64 * 128; idx += 256) {
        int n = idx >> 7, k = idx & 127;
        wot[idx] = __float2bfloat16(W_out[k * 64 + n]);
    }
}

// ---------------------------------------------------------------------------
// kA (MFMA): in-proj (A-frags cvt'd from fp32 x on the fly) -> conv+silu ->
// projections -> s (bf16) + tile sums.
// ---------------------------------------------------------------------------
__global__ __launch_bounds__(256) void kA(
    const float* __restrict__ x,
    const __hip_bfloat16* __restrict__ wti,
    const __hip_bfloat16* __restrict__ wpt,
    const float* __restrict__ conv_w, const float* __restrict__ conv_b,
    const float* __restrict__ b_dt,
    __hip_bfloat16* __restrict__ s, float* __restrict__ sums)
{
    __shared__ __hip_bfloat16 xs[128 * XS_S];   // [c][m] bf16, 15 KB
    __shared__ __hip_bfloat16 xcb[32 * 136];    // [m][k] bf16 conv output, 8.5 KB

    const int t = threadIdx.x;
    const int lane = t & 63;
    const int w = t >> 6;
    const int quad = lane >> 4;
    const int lr = lane & 15;
    const int tile = blockIdx.x;
    const int b = blockIdx.y;
    const int l0 = tile * TILE;

    // ---- phase 1: in-proj (M=48 rows l0-1.., N=128, K=64), B = wti
    {
        floatx4 acc[3][2] = {};
        #pragma unroll
        for (int ks = 0; ks < 2; ++ks) {
            short8 bfr[2];
            #pragma unroll
            for (int j = 0; j < 2; ++j) {
                const int n = w * 32 + j * 16 + lr;
                bfr[j] = *(const short8*)(wti + (n << 6) + ks * 32 + quad * 8);
            }
            #pragma unroll
            for (int mt = 0; mt < 3; ++mt) {
                const long row = (long)l0 - 1 + mt * 16 + lr;
                const bool ok = (row >= 0) && (row < L_LEN);
                const float* xp = x + (((long)b * L_LEN + (ok ? row : 0)) << 6)
                                    + ks * 32 + quad * 8;
                float4 u0 = {0.f,0.f,0.f,0.f}, u1 = {0.f,0.f,0.f,0.f};
                if (ok) { u0 = ((const float4*)xp)[0]; u1 = ((const float4*)xp)[1]; }
                short8 afr = pack_bf8(u0, u1);
                acc[mt][0] = __builtin_amdgcn_mfma_f32_16x16x32_bf16(afr, bfr[0], acc[mt][0], 0, 0, 0);
                acc[mt][1] = __builtin_amdgcn_mfma_f32_16x16x32_bf16(afr, bfr[1], acc[mt][1], 0, 0, 0);
            }
        }
        #pragma unroll
        for (int mt = 0; mt < 3; ++mt)
            #pragma unroll
            for (int j = 0; j < 2; ++j) {
                const int col = w * 32 + j * 16 + lr;
                short4v pk;
                pk.x = f2bf(acc[mt][j][0]); pk.y = f2bf(acc[mt][j][1]);
                pk.z = f2bf(acc[mt][j][2]); pk.w = f2bf(acc[mt][j][3]);
                *(short4v*)&xs[col * XS_S + mt * 16 + quad * 4] = pk;
            }
    }
    __syncthreads();

    // ---- phase 2: depthwise conv(4) + silu -> xcb[m][c] bf16
    {
        const int c = t & 127;
        const int m0 = (t >> 7) * 16;
        const float cw0 = conv_w[c], cw1 = conv_w[128 + c];
        const float cw2 = conv_w[256 + c], cw3 = conv_w[384 + c];
        const float cb = conv_b[c];
        float wb[20];
        #pragma unroll
        for (int j = 0; j < 5; ++j) {
            short4v sv = *(const short4v*)&xs[c * XS_S + m0 + j * 4];
            wb[j*4+0] = bf2f(sv.x); wb[j*4+1] = bf2f(sv.y);
            wb[j*4+2] = bf2f(sv.z); wb[j*4+3] = bf2f(sv.w);
        }
        #pragma unroll
        for (int i = 0; i < 16; ++i) {
            float v = wb[i] * cw0 + wb[i + 1] * cw1 + wb[i + 2] * cw2
                    + wb[i + 3] * cw3 + cb;
            xcb[(m0 + i) * 136 + c] = __float2bfloat16(fast_silu(v));
        }
    }
    __syncthreads();

    // ---- phase 3: projections, s + sums
    {
        floatx4 accx[2][2] = {}, accd[2][2] = {};
        #pragma unroll
        for (int ks = 0; ks < 4; ++ks) {
            short8 afr[2];
            #pragma unroll
            for (int mt = 0; mt < 2; ++mt)
                afr[mt] = *(const short8*)&xcb[(mt * 16 + lr) * 136 + ks * 32 + quad * 8];
            #pragma unroll
            for (int j = 0; j < 2; ++j) {
                const int n = w * 32 + j * 16 + lr;
                short8 bx = *(const short8*)(wpt + (n << 7) + ks * 32 + quad * 8);
                short8 bd = *(const short8*)(wpt + ((n + 128) << 7) + ks * 32 + quad * 8);
                #pragma unroll
                for (int mt = 0; mt < 2; ++mt) {
                    accx[mt][j] = __builtin_amdgcn_mfma_f32_16x16x32_bf16(afr[mt], bx, accx[mt][j], 0, 0, 0);
                    accd[mt][j] = __builtin_amdgcn_mfma_f32_16x16x32_bf16(afr[mt], bd, accd[mt][j], 0, 0, 0);
                }
            }
        }
        const long base = (long)b * L_LEN + l0;
        float ps0 = 0.f, ps1 = 0.f;
        #pragma unroll
        for (int j = 0; j < 2; ++j) {
            const int col = w * 32 + j * 16 + lr;
            const float bdv = b_dt[col];
            float psl = 0.f;
            #pragma unroll
            for (int mt = 0; mt < 2; ++mt) {
                #pragma unroll
                for (int r = 0; r < 4; ++r) {
                    float dv = accd[mt][j][r] + bdv;
                    float sv = accx[mt][j][r] * fast_softplus(dv);
                    __hip_bfloat16 h = __float2bfloat16(sv);
                    s[((base + mt * 16 + quad * 4 + r) << 7) + col] = h;
                    psl += __bfloat162float(h);
                }
            }
            if (j == 0) ps0 = psl; else ps1 = psl;
        }
        ps0 += __shfl_xor(ps0, 16); ps0 += __shfl_xor(ps0, 32);
        ps1 += __shfl_xor(ps1, 16); ps1 += __shfl_xor(ps1, 32);
        const long sb = ((long)b * NT + tile) << 7;
        if (quad == 0)      sums[sb + w * 32 + lr] = ps0;
        else if (quad == 1) sums[sb + w * 32 + 16 + lr] = ps1;
    }
}

// ---------------------------------------------------------------------------
// kB1: per-chunk channel sums. grid(NCH, 2) x 256.
// ---------------------------------------------------------------------------
__global__ __launch_bounds__(256) void kB1(const float* __restrict__ sums,
                                           float* __restrict__ csum)
{
    __shared__ float ps[256];
    const int t = threadIdx.x;
    const int c = t & 127, h = t >> 7;
    const int ch = blockIdx.x, b = blockIdx.y;
    const long tb = ((long)b * NT + ch * TPC + h * 27) * 128 + c;
    float tot = 0.f;
    for (int j = 0; j < 27; j += 9) {
        float v[9];
        #pragma unroll
        for (int k = 0; k < 9; ++k) v[k] = sums[tb + (long)(j + k) * 128];
        #pragma unroll
        for (int k = 0; k < 9; ++k) tot += v[k];
    }
    ps[t] = tot;
    __syncthreads();
    if (t < 128) csum[((long)b * NCH + ch) * 128 + t] = ps[t] + ps[t + 128];
}

// ---------------------------------------------------------------------------
// kB2: exclusive scan over the 64 chunks, per (b, c). 1 block x 256.
// ---------------------------------------------------------------------------
__global__ __launch_bounds__(256) void kB2(float* __restrict__ csum)
{
    const int t = threadIdx.x;
    const int c = t & 127, b = t >> 7;
    const long base = (long)b * NCH * 128 + c;
    float run = 0.f;
    for (int ch = 0; ch < NCH; ch += 8) {
        float v[8];
        #pragma unroll
        for (int k = 0; k < 8; ++k) v[k] = csum[base + (long)(ch + k) * 128];
        #pragma unroll
        for (int k = 0; k < 8; ++k) {
            csum[base + (long)(ch + k) * 128] = run;
            run += v[k];
        }
    }
}

// ---------------------------------------------------------------------------
// kB3: rewrite sums -> exclusive tile prefix (chunk offset + in-chunk scan).
// grid(NCH, 2) x 128.
// ---------------------------------------------------------------------------
__global__ __launch_bounds__(128) void kB3(float* __restrict__ sums,
                                           const float* __restrict__ csum)
{
    const int c = threadIdx.x;
    const int ch = blockIdx.x, b = blockIdx.y;
    float run = csum[((long)b * NCH + ch) * 128 + c];
    const long tb = ((long)b * NT + ch * TPC) * 128 + c;
    for (int j = 0; j < TPC; j += 9) {
        float v[9];
        #pragma unroll
        for (int k = 0; k < 9; ++k) v[k] = sums[tb + (long)(j + k) * 128];
        #pragma unroll
        for (int k = 0; k < 9; ++k) {
            sums[tb + (long)(j + k) * 128] = run;
            run += v[k];
        }
    }
}

// ---------------------------------------------------------------------------
// kC (MFMA): res-proj (A-frags from fp32 x) -> silu -> scan+gate ->
// out-proj MFMA -> residual + LayerNorm(64).
// ---------------------------------------------------------------------------
__global__ __launch_bounds__(256) void kC(
    const float* __restrict__ x,
    const __hip_bfloat16* __restrict__ wtr,
    const __hip_bfloat16* __restrict__ wot,
    const float* __restrict__ gamma, const float* __restrict__ beta,
    const __hip_bfloat16* __restrict__ s, const float* __restrict__ offs,
    float* __restrict__ out)
{
    __shared__ float resf[32 * 128];          // 16 KB; reused as zbuf
    __shared__ __hip_bfloat16 ybf[32 * 136];  // 8.5 KB

    const int t = threadIdx.x;
    const int lane = t & 63;
    const int w = t >> 6;
    const int quad = lane >> 4;
    const int lr = lane & 15;
    const int tile = blockIdx.x;
    const int b = blockIdx.y;
    const int l0 = tile * TILE;
    const long base = (long)b * L_LEN;

    // ---- phase 1: res-proj MFMA (M=32, N=128, K=64), silu -> resf[m][c]
    {
        floatx4 acc[2][2] = {};
        #pragma unroll
        for (int ks = 0; ks < 2; ++ks) {
            short8 bfr[2];
            #pragma unroll
            for (int j = 0; j < 2; ++j) {
                const int n = w * 32 + j * 16 + lr;
                bfr[j] = *(const short8*)(wtr + (n << 6) + ks * 32 + quad * 8);
            }
            #pragma unroll
            for (int mt = 0; mt < 2; ++mt) {
                const float* xp = x + ((base + l0 + mt * 16 + lr) << 6) + ks * 32 + quad * 8;
                float4 u0 = ((const float4*)xp)[0], u1 = ((const float4*)xp)[1];
                short8 afr = pack_bf8(u0, u1);
                acc[mt][0] = __builtin_amdgcn_mfma_f32_16x16x32_bf16(afr, bfr[0], acc[mt][0], 0, 0, 0);
                acc[mt][1] = __builtin_amdgcn_mfma_f32_16x16x32_bf16(afr, bfr[1], acc[mt][1], 0, 0, 0);
            }
        }
        #pragma unroll
        for (int mt = 0; mt < 2; ++mt)
            #pragma unroll
            for (int j = 0; j < 2; ++j) {
                const int col = w * 32 + j * 16 + lr;
                #pragma unroll
                for (int r = 0; r < 4; ++r)
                    resf[(mt * 16 + quad * 4 + r) * 128 + col] = fast_silu(acc[mt][j][r]);
            }
    }
    __syncthreads();

    // ---- phase 2: scan + gate (threads 0..127), y -> ybf bf16
    if (t < 128) {
        float run = offs[((long)b * NT + tile) * 128 + t];
        const __hip_bfloat16* sp = s + ((base + l0) << 7) + t;
        #pragma unroll 8
        for (int q = 0; q < 32; ++q) {
            run += __bfloat162float(sp[q << 7]);
            ybf[q * 136 + t] = __float2bfloat16(resf[q * 128 + t] * run);
        }
    }
    __syncthreads();

    // ---- phase 3: out-proj MFMA (M=32, N=64, K=128) -> zbuf (=resf) [m][68]
    {
        float* zbuf = resf;
        floatx4 acc[2] = {};
        const int n = w * 16 + lr;
        #pragma unroll
        for (int ks = 0; ks < 4; ++ks) {
            short8 bfr = *(const short8*)(wot + (n << 7) + ks * 32 + quad * 8);
            #pragma unroll
            for (int mt = 0; mt < 2; ++mt) {
                short8 afr = *(const short8*)&ybf[(mt * 16 + lr) * 136 + ks * 32 + quad * 8];
                acc[mt] = __builtin_amdgcn_mfma_f32_16x16x32_bf16(afr, bfr, acc[mt], 0, 0, 0);
            }
        }
        __syncthreads();
        #pragma unroll
        for (int mt = 0; mt < 2; ++mt)
            #pragma unroll
            for (int r = 0; r < 4; ++r)
                zbuf[(mt * 16 + quad * 4 + r) * 68 + n] = acc[mt][r];
    }
    __syncthreads();

    // ---- phase 4: residual + LayerNorm(64)
    {
        const float* zbuf = resf;
        const int d = t & 63;
        const int dg = t >> 6;
        const float g  = gamma[d];
        const float bt = beta[d];
        #pragma unroll 2
        for (int i = 0; i < 8; ++i) {
            int q = dg + 4 * i;
            float z = zbuf[q * 68 + d] + x[(base + l0 + q) * 64 + d];
            float zsum = z;
            #pragma unroll
            for (int off = 32; off > 0; off >>= 1) zsum += __shfl_xor(zsum, off);
            float mu = zsum * 0.015625f;
            float dz = z - mu;
            float vsum = dz * dz;
            #pragma unroll
            for (int off = 32; off > 0; off >>= 1) vsum += __shfl_xor(vsum, off);
            float inv = rsqrtf(vsum * 0.015625f + 1e-3f);
            out[(base + l0 + q) * 64 + d] = g * dz * inv + bt;
        }
    }
}

extern "C" void kernel_launch(void* const* d_in, const int* in_sizes, int n_in,
                              void* d_out, int out_size, void* d_ws, size_t ws_size,
                              hipStream_t stream) {
    const float* x      = (const float*)d_in[0];
    const float* W_in   = (const float*)d_in[1];
    const float* conv_w = (const float*)d_in[2];
    const float* conv_b = (const float*)d_in[3];
    const float* W_x    = (const float*)d_in[4];
    const float* W_dt   = (const float*)d_in[5];
    const float* b_dt   = (const float*)d_in[6];
    const float* W_out  = (const float*)d_in[7];
    const float* gamma  = (const float*)d_in[8];
    const float* beta   = (const float*)d_in[9];
    float* out = (float*)d_out;

    // workspace layout (bytes)
    __hip_bfloat16* s    = (__hip_bfloat16*)d_ws;                        // 56,623,104
    float*          sums = (float*)((char*)d_ws + 56623104);             //  3,538,944
    float*          csum = (float*)((char*)d_ws + 60162048);             //     65,536
    __hip_bfloat16* wti  = (__hip_bfloat16*)((char*)d_ws + 88477696);    //     16,384
    __hip_bfloat16* wpt  = (__hip_bfloat16*)((char*)d_ws + 88494080);    //     65,536
    __hip_bfloat16* wtr  = (__hip_bfloat16*)((char*)d_ws + 88559616);    //     16,384
    __hip_bfloat16* wot  = (__hip_bfloat16*)((char*)d_ws + 88576000);    //     16,384

    kW_w<<<1, 256, 0, stream>>>(W_in, W_x, W_dt, W_out, wti, wpt, wtr, wot);
    dim3 grid(NT, 2);
    kA<<<grid, 256, 0, stream>>>(x, wti, wpt, conv_w, conv_b, b_dt, s, sums);
    dim3 gridB(NCH, 2);
    kB1<<<gridB, 256, 0, stream>>>(sums, csum);
    kB2<<<1, 256, 0, stream>>>(csum);
    kB3<<<gridB, 128, 0, stream>>>(sums, csum);
    kC<<<grid, 256, 0, stream>>>(x, wtr, wot, gamma, beta, s, sums, out);
}